// Round 4
// baseline (72.417 us; speedup 1.0000x reference)
//
#include <hip/hip_runtime.h>

// EdgeNetwork: out[e] = sigmoid( tanh( [x[col[e]], x[row[e]]] @ W1 + b1 ) @ W2 + b2 )
// E = 3.2M, IN=16, HID=64.
//
// R4: same 32-edge-tile mfma_32x32x16 structure as R3, two changes:
//  1) exp2/rcp via single-instruction inline asm (v_exp_f32 / v_rcp_f32).
//     R3's RCPF macro likely fell back to IEEE 1.0f/x (~10-op divide) --
//     +640 cy/tile, which exactly explains the measured 40us VALU-busy.
//  2) EXACT template path (E % 32 == 0): no per-lane index clamp, no store
//     bound check.
// tanh folded: W1,b1 pre-scaled by 2*log2e, tanh = 1 - 2*rcp(1+exp2(a));
// w2*tanh accumulated as pbase(=sum w2) + sum(-2*w2*rcp(...)).
// 2-deep pipeline: idx for t+2, gathers for t+1 in flight during compute of t.

typedef __attribute__((ext_vector_type(8)))  short bf16x8;
typedef __attribute__((ext_vector_type(2)))  float f32x2;
typedef __attribute__((ext_vector_type(4)))  float f32x4;
typedef __attribute__((ext_vector_type(16))) float f32x16;
typedef __attribute__((ext_vector_type(4)))  unsigned short u16x4;

#define LOG2E 1.4426950408889634f

// Guaranteed single-instruction transcendentals (no macro/builtin lottery).
__device__ __forceinline__ float asm_exp2(float x) {
    float r;
    asm("v_exp_f32 %0, %1" : "=v"(r) : "v"(x));
    return r;
}
__device__ __forceinline__ float asm_rcp(float x) {
    float r;
    asm("v_rcp_f32 %0, %1" : "=v"(r) : "v"(x));
    return r;
}

template <bool B> struct BC { static constexpr bool value = B; };

__device__ __forceinline__ unsigned short f2bf(float f) {
    unsigned u = __float_as_uint(f);
    u += 0x7fffu + ((u >> 16) & 1u);
    return (unsigned short)(u >> 16);
}

// ---- x fp32 -> bf16, plus edge_index dtype detection (block 0, wave 0) ----
__global__ void prep(const float* __restrict__ x, unsigned short* __restrict__ xb, int n,
                     const unsigned* __restrict__ ei, int* __restrict__ flag) {
    if (blockIdx.x == 0 && threadIdx.x < 64) {
        unsigned v = ei[2 * threadIdx.x + 1];          // odd 32-bit words
        unsigned long long nz = __ballot(v != 0u);
        if (threadIdx.x == 0) flag[0] = (nz == 0ull) ? 1 : 0;
    }
    int i = (blockIdx.x * blockDim.x + threadIdx.x) * 4;
    if (i >= n) return;
    f32x4 v = *(const f32x4*)(x + i);
    u16x4 o;
    o[0] = f2bf(v[0]); o[1] = f2bf(v[1]); o[2] = f2bf(v[2]); o[3] = f2bf(v[3]);
    *(u16x4*)(xb + i) = o;
}

__global__ void detect_idx64(const unsigned* __restrict__ ei, int* __restrict__ flag) {
    unsigned v = ei[2 * threadIdx.x + 1];
    unsigned long long nz = __ballot(v != 0u);
    if (threadIdx.x == 0) flag[0] = (nz == 0ull) ? 1 : 0;
}

struct IdxPair { int c, r; };

template <bool USE_XB, bool EXACT>
__global__ void __launch_bounds__(256)
edge_mlp(const void* __restrict__ ei,
         const float* __restrict__ x,
         const unsigned short* __restrict__ xb,
         const float* __restrict__ W1,
         const float* __restrict__ b1,
         const float* __restrict__ W2,
         const float* __restrict__ b2,
         float* __restrict__ out,
         const int* __restrict__ flag,
         int E, int ntiles)
{
    const int lane = threadIdx.x & 63;
    const int l31  = lane & 31;        // edge within tile (B col) / W1T row (hid)
    const int g    = lane >> 5;        // k-slot group (features 8g..8g+7)
    const int gwave  = blockIdx.x * (blockDim.x >> 6) + (threadIdx.x >> 6);
    const int nwaves = gridDim.x * (blockDim.x >> 6);

    const int idx64 = flag ? flag[0] : 0;
    const float S = 2.0f * LOG2E;

    // A-fragments of S*W1T: lane supplies A[row=l31][k-slot b] = S*W1[16*ks+8*g+b][32*blk+l31]
    bf16x8 w1f00, w1f01, w1f10, w1f11;
    {
        union { bf16x8 v; unsigned short u[8]; } t00, t01, t10, t11;
#pragma unroll
        for (int b = 0; b < 8; ++b) {
            int k0 = 8 * g + b;
            t00.u[b] = f2bf(S * W1[(k0)      * 64 + l31]);
            t01.u[b] = f2bf(S * W1[(16 + k0) * 64 + l31]);
            t10.u[b] = f2bf(S * W1[(k0)      * 64 + 32 + l31]);
            t11.u[b] = f2bf(S * W1[(16 + k0) * 64 + 32 + l31]);
        }
        w1f00 = t00.v; w1f01 = t01.v; w1f10 = t10.v; w1f11 = t11.v;
    }
    // C/D row layout (32x32): row = (reg&3) + 8*(reg>>2) + 4*g, col = l31
    f32x16 b1v0, b1v1;
    f32x2  w2a[8], w2b[8];
    float  pbase = 0.f;
#pragma unroll
    for (int reg = 0; reg < 16; ++reg) {
        int rowv = (reg & 3) + 8 * (reg >> 2) + 4 * g;
        b1v0[reg] = S * b1[rowv];
        b1v1[reg] = S * b1[32 + rowv];
        float wa = W2[rowv], wb = W2[32 + rowv];
        w2a[reg >> 1][reg & 1] = -2.0f * wa;
        w2b[reg >> 1][reg & 1] = -2.0f * wb;
        pbase += wa + wb;
    }
    const float bias2 = b2[0];

    auto body = [&](auto bc) {
        constexpr bool IDX64 = decltype(bc)::value;
        auto load_idx = [&](int tt) -> IdxPair {
            int e = tt * 32 + l31;
            int ec;
            if (EXACT) ec = e;
            else       ec = e < E ? e : E - 1;
            IdxPair ip;
            if (IDX64) {
                ip.r = ((const int*)ei)[2 * (size_t)ec];             // low word
                ip.c = ((const int*)ei)[2 * ((size_t)E + ec)];
            } else {
                ip.r = ((const int*)ei)[(size_t)ec];
                ip.c = ((const int*)ei)[(size_t)E + ec];
            }
            return ip;
        };
        auto gather = [&](int node) -> bf16x8 {
            if (USE_XB) {
                return *(const bf16x8*)(xb + (size_t)node * 16 + 8 * g);
            } else {
                const float* px = x + (size_t)node * 16 + 8 * g;
                f32x4 v0 = *(const f32x4*)px;
                f32x4 v1 = *(const f32x4*)(px + 4);
                union { bf16x8 v; unsigned short u[8]; } t;
#pragma unroll
                for (int b = 0; b < 4; ++b) { t.u[b] = f2bf(v0[b]); t.u[b + 4] = f2bf(v1[b]); }
                return t.v;
            }
        };

        int t = gwave;
        if (t >= ntiles) return;
        IdxPair ic = load_idx(t);
        bf16x8 fc = gather(ic.c);
        bf16x8 fr = gather(ic.r);
        int tn = t + nwaves;
        IdxPair inx = load_idx(tn < ntiles ? tn : ntiles - 1);

        while (true) {
            // prefetch: gathers for t+1, indices for t+2 (issue before compute)
            bf16x8 fcn = gather(inx.c);
            bf16x8 frn = gather(inx.r);
            int tnn = tn + nwaves;
            IdxPair inn = load_idx(tnn < ntiles ? tnn : ntiles - 1);

            // layer 1: 2 hid-blocks x 2 K-halves
            f32x16 acc0 = __builtin_amdgcn_mfma_f32_32x32x16_bf16(w1f00, fc, b1v0, 0, 0, 0);
            acc0        = __builtin_amdgcn_mfma_f32_32x32x16_bf16(w1f01, fr, acc0, 0, 0, 0);
            f32x16 acc1 = __builtin_amdgcn_mfma_f32_32x32x16_bf16(w1f10, fc, b1v1, 0, 0, 0);
            acc1        = __builtin_amdgcn_mfma_f32_32x32x16_bf16(w1f11, fr, acc1, 0, 0, 0);

            // layer 2: p = sum w2*tanh = pbase + sum(-2*w2 * rcp(1+exp2(acc)))
            f32x2 pv0 = { pbase, 0.0f };
            f32x2 pv1 = { 0.0f, 0.0f };
#pragma unroll
            for (int j = 0; j < 8; ++j) {
                f32x2 rv0 = { asm_rcp(1.0f + asm_exp2(acc0[2 * j])),
                              asm_rcp(1.0f + asm_exp2(acc0[2 * j + 1])) };
                f32x2 rv1 = { asm_rcp(1.0f + asm_exp2(acc1[2 * j])),
                              asm_rcp(1.0f + asm_exp2(acc1[2 * j + 1])) };
                pv0 += w2a[j] * rv0;
                pv1 += w2b[j] * rv1;
            }
            float p = (pv0[0] + pv1[0]) + (pv0[1] + pv1[1]);
            p += __shfl_xor(p, 32);
            float z = p + bias2;
            float res = asm_rcp(1.0f + asm_exp2(-z * LOG2E));
            int e0i = t * 32 + l31;
            if (EXACT) {
                if (lane < 32) out[e0i] = res;          // tile always full
            } else {
                if (lane < 32 && e0i < E) out[e0i] = res;
            }

            if (tn >= ntiles) break;
            t = tn; tn = tnn;
            inx = inn; fc = fcn; fr = frn;
        }
    };

    if (idx64) body(BC<true>{});
    else       body(BC<false>{});
}

extern "C" void kernel_launch(void* const* d_in, const int* in_sizes, int n_in,
                              void* d_out, int out_size, void* d_ws, size_t ws_size,
                              hipStream_t stream)
{
    const float* x  = (const float*)d_in[0];
    const void*  ei = d_in[1];
    const float* W1 = (const float*)d_in[2];
    const float* b1 = (const float*)d_in[3];
    const float* W2 = (const float*)d_in[4];
    const float* b2 = (const float*)d_in[5];
    float* out = (float*)d_out;

    const int E      = in_sizes[1] / 2;
    const int nx     = in_sizes[0];
    const int ntiles = (E + 31) / 32;
    const bool exact = (E % 32) == 0;

    int* flag = nullptr;
    unsigned short* xb = nullptr;
    bool use_xb = false;
    if (ws_size >= 4) flag = (int*)d_ws;
    if (ws_size >= 256 + (size_t)nx * 2) {
        xb = (unsigned short*)((char*)d_ws + 256);
        use_xb = true;
    }

    if (use_xb) {
        int nth = (nx + 3) / 4;
        prep<<<(nth + 255) / 256, 256, 0, stream>>>(x, xb, nx, (const unsigned*)ei, flag);
    } else if (flag) {
        detect_idx64<<<1, 64, 0, stream>>>((const unsigned*)ei, flag);
    }

    const int blocks = 2048;
    if (use_xb) {
        if (exact) edge_mlp<true , true ><<<blocks, 256, 0, stream>>>(ei, x, xb, W1, b1, W2, b2, out, flag, E, ntiles);
        else       edge_mlp<true , false><<<blocks, 256, 0, stream>>>(ei, x, xb, W1, b1, W2, b2, out, flag, E, ntiles);
    } else {
        if (exact) edge_mlp<false, true ><<<blocks, 256, 0, stream>>>(ei, x, xb, W1, b1, W2, b2, out, flag, E, ntiles);
        else       edge_mlp<false, false><<<blocks, 256, 0, stream>>>(ei, x, xb, W1, b1, W2, b2, out, flag, E, ntiles);
    }
}

// Round 5
// 62.929 us; speedup vs baseline: 1.1508x; 1.1508x over previous
//
#include <hip/hip_runtime.h>

// EdgeNetwork: out[e] = sigmoid( tanh( [x[col[e]], x[row[e]]] @ W1 + b1 ) @ W2 + b2 )
// E = 3.2M, IN=16, HID=64.
//
// R5: same 32-edge-tile mfma_32x32x16 structure; register-pressure attack:
//  - MFMA C = inline zero; b1 folded through exp2:
//      rcp(1 + exp2(S*(W1x) + S*b1)) = rcp(fma(exp2(S*b1), exp2(acc), 1))
//  - per-row constants (exp2(S*b1[h]), -2*W2[h]) live in a 512B LDS broadcast
//    table (half-wave-uniform reads, conflict-free) instead of 64 VGPRs.
//  - 32-bit addressing (SGPR base + u32 voffset) for idx/gather/store.
//  - scalar epilogue (no f32x2) to kill pack/unpack movs around trans ops.
// 2-deep pipeline: idx for t+2, gathers for t+1 in flight during compute of t.

typedef __attribute__((ext_vector_type(8)))  short bf16x8;
typedef __attribute__((ext_vector_type(4)))  float f32x4;
typedef __attribute__((ext_vector_type(16))) float f32x16;
typedef __attribute__((ext_vector_type(4)))  unsigned short u16x4;

#define LOG2E 1.4426950408889634f

__device__ __forceinline__ float asm_exp2(float x) {
    float r;
    asm("v_exp_f32 %0, %1" : "=v"(r) : "v"(x));
    return r;
}
__device__ __forceinline__ float asm_rcp(float x) {
    float r;
    asm("v_rcp_f32 %0, %1" : "=v"(r) : "v"(x));
    return r;
}

template <bool B> struct BC { static constexpr bool value = B; };

__device__ __forceinline__ unsigned short f2bf(float f) {
    unsigned u = __float_as_uint(f);
    u += 0x7fffu + ((u >> 16) & 1u);
    return (unsigned short)(u >> 16);
}

// ---- x fp32 -> bf16, plus edge_index dtype detection (block 0, wave 0) ----
__global__ void prep(const float* __restrict__ x, unsigned short* __restrict__ xb, int n,
                     const unsigned* __restrict__ ei, int* __restrict__ flag) {
    if (blockIdx.x == 0 && threadIdx.x < 64) {
        unsigned v = ei[2 * threadIdx.x + 1];          // odd 32-bit words
        unsigned long long nz = __ballot(v != 0u);
        if (threadIdx.x == 0) flag[0] = (nz == 0ull) ? 1 : 0;
    }
    int i = (blockIdx.x * blockDim.x + threadIdx.x) * 4;
    if (i >= n) return;
    f32x4 v = *(const f32x4*)(x + i);
    u16x4 o;
    o[0] = f2bf(v[0]); o[1] = f2bf(v[1]); o[2] = f2bf(v[2]); o[3] = f2bf(v[3]);
    *(u16x4*)(xb + i) = o;
}

__global__ void detect_idx64(const unsigned* __restrict__ ei, int* __restrict__ flag) {
    unsigned v = ei[2 * threadIdx.x + 1];
    unsigned long long nz = __ballot(v != 0u);
    if (threadIdx.x == 0) flag[0] = (nz == 0ull) ? 1 : 0;
}

struct IdxPair { int c, r; };

template <bool USE_XB, bool EXACT>
__global__ void __launch_bounds__(256)
edge_mlp(const void* __restrict__ ei,
         const float* __restrict__ x,
         const unsigned short* __restrict__ xb,
         const float* __restrict__ W1,
         const float* __restrict__ b1,
         const float* __restrict__ W2,
         const float* __restrict__ b2,
         float* __restrict__ out,
         const int* __restrict__ flag,
         int E, int ntiles)
{
    __shared__ float2 tbl[64];   // [g][blk][j] -> (exp2(S*b1[h]), -2*W2[h])

    const int lane = threadIdx.x & 63;
    const int l31  = lane & 31;        // edge within tile (B col) / W1T row (hid)
    const int g    = lane >> 5;        // k-slot group (features 8g..8g+7)
    const int gwave  = blockIdx.x * (blockDim.x >> 6) + (threadIdx.x >> 6);
    const int nwaves = gridDim.x * (blockDim.x >> 6);

    const int idx64 = flag ? flag[0] : 0;
    const float S = 2.0f * LOG2E;

    // LDS constant table: index tid = tg*32 + tb*16 + tj
    {
        int tid = threadIdx.x;
        if (tid < 64) {
            int tg = tid >> 5, tb = (tid >> 4) & 1, tj = tid & 15;
            int rowv = (tj & 3) + 8 * (tj >> 2) + 4 * tg;
            int h = 32 * tb + rowv;
            float2 cw;
            cw.x = exp2f(S * b1[h]);
            cw.y = -2.0f * W2[h];
            tbl[tid] = cw;
        }
    }

    // A-fragments of S*W1T: lane supplies A[row=l31][k-slot b] = S*W1[16*ks+8*g+b][32*blk+l31]
    bf16x8 w1f00, w1f01, w1f10, w1f11;
    {
        union { bf16x8 v; unsigned short u[8]; } t00, t01, t10, t11;
#pragma unroll
        for (int b = 0; b < 8; ++b) {
            int k0 = 8 * g + b;
            t00.u[b] = f2bf(S * W1[(k0)      * 64 + l31]);
            t01.u[b] = f2bf(S * W1[(16 + k0) * 64 + l31]);
            t10.u[b] = f2bf(S * W1[(k0)      * 64 + 32 + l31]);
            t11.u[b] = f2bf(S * W1[(16 + k0) * 64 + 32 + l31]);
        }
        w1f00 = t00.v; w1f01 = t01.v; w1f10 = t10.v; w1f11 = t11.v;
    }

    // pbase = sum of this lane's 32 W2 values (p = pbase + sum(-2*w2*rcp))
    float pbase = 0.f;
#pragma unroll
    for (int j = 0; j < 16; ++j) {
        int rowv = (j & 3) + 8 * (j >> 2) + 4 * g;
        pbase += W2[rowv] + W2[32 + rowv];
    }
    const float bias2 = b2[0];

    __syncthreads();
    const float2* tb = &tbl[g * 32];   // per-lane base; blk/j offsets are immediates

    const char* xbb  = (const char*)xb;
    const char* outb = (char*)out;
    const unsigned g16 = (unsigned)g << 4;

    auto body = [&](auto bc) {
        constexpr bool IDX64 = decltype(bc)::value;
        const unsigned sh = IDX64 ? 3u : 2u;
        const char* eiR = (const char*)ei;
        const char* eiC = (const char*)ei + ((size_t)E << sh);

        auto load_idx = [&](int tt) -> IdxPair {
            int e = tt * 32 + l31;
            unsigned ec;
            if (EXACT) ec = (unsigned)e;
            else       ec = (unsigned)(e < E ? e : E - 1);
            unsigned off = ec << sh;
            IdxPair ip;
            ip.r = *(const int*)(eiR + off);    // low word works for both dtypes
            ip.c = *(const int*)(eiC + off);
            return ip;
        };
        auto gather = [&](int node) -> bf16x8 {
            if (USE_XB) {
                unsigned off = ((unsigned)node << 5) + g16;
                return *(const bf16x8*)(xbb + off);
            } else {
                const float* px = x + (size_t)node * 16 + 8 * g;
                f32x4 v0 = *(const f32x4*)px;
                f32x4 v1 = *(const f32x4*)(px + 4);
                union { bf16x8 v; unsigned short u[8]; } t;
#pragma unroll
                for (int b = 0; b < 4; ++b) { t.u[b] = f2bf(v0[b]); t.u[b + 4] = f2bf(v1[b]); }
                return t.v;
            }
        };

        int t = gwave;
        if (t >= ntiles) return;
        IdxPair ic = load_idx(t);
        bf16x8 fc = gather(ic.c);
        bf16x8 fr = gather(ic.r);
        int tn = t + nwaves;
        IdxPair inx = load_idx(tn < ntiles ? tn : ntiles - 1);

        const f32x16 ZC = 0.0f;   // splat zero; folds to MFMA inline-const C

        while (true) {
            // prefetch: gathers for t+1, indices for t+2 (issue before compute)
            bf16x8 fcn = gather(inx.c);
            bf16x8 frn = gather(inx.r);
            int tnn = tn + nwaves;
            IdxPair inn = load_idx(tnn < ntiles ? tnn : ntiles - 1);

            // layer 1: 2 hid-blocks x 2 K-halves, zero C
            f32x16 acc0 = __builtin_amdgcn_mfma_f32_32x32x16_bf16(w1f00, fc, ZC, 0, 0, 0);
            acc0        = __builtin_amdgcn_mfma_f32_32x32x16_bf16(w1f01, fr, acc0, 0, 0, 0);
            f32x16 acc1 = __builtin_amdgcn_mfma_f32_32x32x16_bf16(w1f10, fc, ZC, 0, 0, 0);
            acc1        = __builtin_amdgcn_mfma_f32_32x32x16_bf16(w1f11, fr, acc1, 0, 0, 0);

            // layer 2: p = pbase + sum(-2*w2 * rcp(1 + eb*exp2(acc)))
            float p0 = pbase, p1 = 0.f, p2 = 0.f, p3 = 0.f;
#pragma unroll
            for (int j = 0; j < 16; ++j) {
                float2 cw = tb[j];
                float e  = asm_exp2(acc0[j]);
                float rv = asm_rcp(fmaf(cw.x, e, 1.0f));
                float pj = fmaf(cw.y, rv, (j & 3) == 0 ? p0 : (j & 3) == 1 ? p1 : (j & 3) == 2 ? p2 : p3);
                if      ((j & 3) == 0) p0 = pj;
                else if ((j & 3) == 1) p1 = pj;
                else if ((j & 3) == 2) p2 = pj;
                else                   p3 = pj;
            }
#pragma unroll
            for (int j = 0; j < 16; ++j) {
                float2 cw = tb[16 + j];
                float e  = asm_exp2(acc1[j]);
                float rv = asm_rcp(fmaf(cw.x, e, 1.0f));
                float pj = fmaf(cw.y, rv, (j & 3) == 0 ? p0 : (j & 3) == 1 ? p1 : (j & 3) == 2 ? p2 : p3);
                if      ((j & 3) == 0) p0 = pj;
                else if ((j & 3) == 1) p1 = pj;
                else if ((j & 3) == 2) p2 = pj;
                else                   p3 = pj;
            }
            float p = (p0 + p1) + (p2 + p3);
            p += __shfl_xor(p, 32);
            float z = p + bias2;
            float res = asm_rcp(1.0f + asm_exp2(-z * LOG2E));

            unsigned eoff = ((unsigned)(t * 32 + l31)) << 2;
            if (EXACT) {
                if (lane < 32) *(float*)(outb + eoff) = res;
            } else {
                if (lane < 32 && (t * 32 + l31) < E) *(float*)(outb + eoff) = res;
            }

            if (tn >= ntiles) break;
            t = tn; tn = tnn;
            inx = inn; fc = fcn; fr = frn;
        }
    };

    if (idx64) body(BC<true>{});
    else       body(BC<false>{});
}

extern "C" void kernel_launch(void* const* d_in, const int* in_sizes, int n_in,
                              void* d_out, int out_size, void* d_ws, size_t ws_size,
                              hipStream_t stream)
{
    const float* x  = (const float*)d_in[0];
    const void*  ei = d_in[1];
    const float* W1 = (const float*)d_in[2];
    const float* b1 = (const float*)d_in[3];
    const float* W2 = (const float*)d_in[4];
    const float* b2 = (const float*)d_in[5];
    float* out = (float*)d_out;

    const int E      = in_sizes[1] / 2;
    const int nx     = in_sizes[0];
    const int ntiles = (E + 31) / 32;
    const bool exact = (E % 32) == 0;

    int* flag = nullptr;
    unsigned short* xb = nullptr;
    bool use_xb = false;
    if (ws_size >= 4) flag = (int*)d_ws;
    if (ws_size >= 256 + (size_t)nx * 2) {
        xb = (unsigned short*)((char*)d_ws + 256);
        use_xb = true;
    }

    if (use_xb) {
        int nth = (nx + 3) / 4;
        prep<<<(nth + 255) / 256, 256, 0, stream>>>(x, xb, nx, (const unsigned*)ei, flag);
    } else if (flag) {
        detect_idx64<<<1, 64, 0, stream>>>((const unsigned*)ei, flag);
    }

    const int blocks = 2048;
    if (use_xb) {
        if (exact) edge_mlp<true , true ><<<blocks, 256, 0, stream>>>(ei, x, xb, W1, b1, W2, b2, out, flag, E, ntiles);
        else       edge_mlp<true , false><<<blocks, 256, 0, stream>>>(ei, x, xb, W1, b1, W2, b2, out, flag, E, ntiles);
    } else {
        if (exact) edge_mlp<false, true ><<<blocks, 256, 0, stream>>>(ei, x, xb, W1, b1, W2, b2, out, flag, E, ntiles);
        else       edge_mlp<false, false><<<blocks, 256, 0, stream>>>(ei, x, xb, W1, b1, W2, b2, out, flag, E, ntiles);
    }
}

// Round 6
// 62.644 us; speedup vs baseline: 1.1560x; 1.0045x over previous
//
#include <hip/hip_runtime.h>

// EdgeNetwork: out[e] = sigmoid( tanh( [x[col[e]], x[row[e]]] @ W1 + b1 ) @ W2 + b2 )
// E = 3.2M, IN=16, HID=64.
//
// R6: R5 structure (32-edge mfma_32x32x16 tiles, LDS const table, 32-bit addr,
// 2-deep prefetch) + two changes:
//  1) Quad-grouped reciprocal tree: sum_i n_i/D_i over 4 hidden units computed
//     over a common denominator -> 1 v_rcp per 4 h instead of 4. Trans ops per
//     tile drop 64 -> 40 (exp2 per h is irreducible); VALU issue model
//     1084 -> ~860 cyc/tile at the measured ~12cyc/trans rate.
//  2) Balanced launch: 1250 blocks = 5000 waves x exactly 20 tiles (was 8192
//     waves x 12.2 -> ragged 12/13 tail).
// tanh folded: W1,b1 pre-scaled by 2*log2e; D = 1 + exp2(S*b1)*exp2(acc);
// w2*tanh = w2 - 2*w2/D, accumulated as pbase(=sum w2) + sum(n_i/D_i), n=-2*w2.

typedef __attribute__((ext_vector_type(8)))  short bf16x8;
typedef __attribute__((ext_vector_type(4)))  float f32x4;
typedef __attribute__((ext_vector_type(16))) float f32x16;
typedef __attribute__((ext_vector_type(4)))  unsigned short u16x4;

#define LOG2E 1.4426950408889634f

__device__ __forceinline__ float asm_exp2(float x) {
    float r;
    asm("v_exp_f32 %0, %1" : "=v"(r) : "v"(x));
    return r;
}
__device__ __forceinline__ float asm_rcp(float x) {
    float r;
    asm("v_rcp_f32 %0, %1" : "=v"(r) : "v"(x));
    return r;
}

template <bool B> struct BC { static constexpr bool value = B; };

__device__ __forceinline__ unsigned short f2bf(float f) {
    unsigned u = __float_as_uint(f);
    u += 0x7fffu + ((u >> 16) & 1u);
    return (unsigned short)(u >> 16);
}

// ---- x fp32 -> bf16, plus edge_index dtype detection (block 0, wave 0) ----
__global__ void prep(const float* __restrict__ x, unsigned short* __restrict__ xb, int n,
                     const unsigned* __restrict__ ei, int* __restrict__ flag) {
    if (blockIdx.x == 0 && threadIdx.x < 64) {
        unsigned v = ei[2 * threadIdx.x + 1];          // odd 32-bit words
        unsigned long long nz = __ballot(v != 0u);
        if (threadIdx.x == 0) flag[0] = (nz == 0ull) ? 1 : 0;
    }
    int i = (blockIdx.x * blockDim.x + threadIdx.x) * 4;
    if (i >= n) return;
    f32x4 v = *(const f32x4*)(x + i);
    u16x4 o;
    o[0] = f2bf(v[0]); o[1] = f2bf(v[1]); o[2] = f2bf(v[2]); o[3] = f2bf(v[3]);
    *(u16x4*)(xb + i) = o;
}

__global__ void detect_idx64(const unsigned* __restrict__ ei, int* __restrict__ flag) {
    unsigned v = ei[2 * threadIdx.x + 1];
    unsigned long long nz = __ballot(v != 0u);
    if (threadIdx.x == 0) flag[0] = (nz == 0ull) ? 1 : 0;
}

struct IdxPair { int c, r; };

template <bool USE_XB, bool EXACT>
__global__ void __launch_bounds__(256)
edge_mlp(const void* __restrict__ ei,
         const float* __restrict__ x,
         const unsigned short* __restrict__ xb,
         const float* __restrict__ W1,
         const float* __restrict__ b1,
         const float* __restrict__ W2,
         const float* __restrict__ b2,
         float* __restrict__ out,
         const int* __restrict__ flag,
         int E, int ntiles)
{
    __shared__ float2 tbl[64];   // [g][blk][j] -> (exp2(S*b1[h]), -2*W2[h])

    const int lane = threadIdx.x & 63;
    const int l31  = lane & 31;        // edge within tile (B col) / W1T row (hid)
    const int g    = lane >> 5;        // k-slot group (features 8g..8g+7)
    const int gwave  = blockIdx.x * (blockDim.x >> 6) + (threadIdx.x >> 6);
    const int nwaves = gridDim.x * (blockDim.x >> 6);

    const int idx64 = flag ? flag[0] : 0;
    const float S = 2.0f * LOG2E;

    // LDS constant table: index tid = tg*32 + tb*16 + tj
    {
        int tid = threadIdx.x;
        if (tid < 64) {
            int tg = tid >> 5, tb = (tid >> 4) & 1, tj = tid & 15;
            int rowv = (tj & 3) + 8 * (tj >> 2) + 4 * tg;
            int h = 32 * tb + rowv;
            float2 cw;
            cw.x = exp2f(S * b1[h]);
            cw.y = -2.0f * W2[h];
            tbl[tid] = cw;
        }
    }

    // A-fragments of S*W1T: lane supplies A[row=l31][k-slot b] = S*W1[16*ks+8*g+b][32*blk+l31]
    bf16x8 w1f00, w1f01, w1f10, w1f11;
    {
        union { bf16x8 v; unsigned short u[8]; } t00, t01, t10, t11;
#pragma unroll
        for (int b = 0; b < 8; ++b) {
            int k0 = 8 * g + b;
            t00.u[b] = f2bf(S * W1[(k0)      * 64 + l31]);
            t01.u[b] = f2bf(S * W1[(16 + k0) * 64 + l31]);
            t10.u[b] = f2bf(S * W1[(k0)      * 64 + 32 + l31]);
            t11.u[b] = f2bf(S * W1[(16 + k0) * 64 + 32 + l31]);
        }
        w1f00 = t00.v; w1f01 = t01.v; w1f10 = t10.v; w1f11 = t11.v;
    }

    // pbase = sum of this lane's 32 W2 values (p = pbase + sum(n_i/D_i))
    float pbase = 0.f;
#pragma unroll
    for (int j = 0; j < 16; ++j) {
        int rowv = (j & 3) + 8 * (j >> 2) + 4 * g;
        pbase += W2[rowv] + W2[32 + rowv];
    }
    const float bias2 = b2[0];

    __syncthreads();
    // float4 view: t4[m] = (eb[2m], n[2m], eb[2m+1], n[2m+1]) within this g's 32 rows
    const float4* t4 = (const float4*)(&tbl[g * 32]);

    const char* xbb  = (const char*)xb;
    const char* outb = (char*)out;
    const unsigned g16 = (unsigned)g << 4;

    auto body = [&](auto bc) {
        constexpr bool IDX64 = decltype(bc)::value;
        const unsigned sh = IDX64 ? 3u : 2u;
        const char* eiR = (const char*)ei;
        const char* eiC = (const char*)ei + ((size_t)E << sh);

        auto load_idx = [&](int tt) -> IdxPair {
            int e = tt * 32 + l31;
            unsigned ec;
            if (EXACT) ec = (unsigned)e;
            else       ec = (unsigned)(e < E ? e : E - 1);
            unsigned off = ec << sh;
            IdxPair ip;
            ip.r = *(const int*)(eiR + off);    // low word works for both dtypes
            ip.c = *(const int*)(eiC + off);
            return ip;
        };
        auto gather = [&](int node) -> bf16x8 {
            if (USE_XB) {
                unsigned off = ((unsigned)node << 5) + g16;
                return *(const bf16x8*)(xbb + off);
            } else {
                const float* px = x + (size_t)node * 16 + 8 * g;
                f32x4 v0 = *(const f32x4*)px;
                f32x4 v1 = *(const f32x4*)(px + 4);
                union { bf16x8 v; unsigned short u[8]; } t;
#pragma unroll
                for (int b = 0; b < 4; ++b) { t.u[b] = f2bf(v0[b]); t.u[b + 4] = f2bf(v1[b]); }
                return t.v;
            }
        };

        int t = gwave;
        if (t >= ntiles) return;
        IdxPair ic = load_idx(t);
        bf16x8 fc = gather(ic.c);
        bf16x8 fr = gather(ic.r);
        int tn = t + nwaves;
        IdxPair inx = load_idx(tn < ntiles ? tn : ntiles - 1);

        const f32x16 ZC = 0.0f;   // splat zero; folds to MFMA inline-const C

        while (true) {
            // prefetch: gathers for t+1, indices for t+2 (issue before compute)
            bf16x8 fcn = gather(inx.c);
            bf16x8 frn = gather(inx.r);
            int tnn = tn + nwaves;
            IdxPair inn = load_idx(tnn < ntiles ? tnn : ntiles - 1);

            // layer 1: 2 hid-blocks x 2 K-halves, zero C
            f32x16 acc0 = __builtin_amdgcn_mfma_f32_32x32x16_bf16(w1f00, fc, ZC, 0, 0, 0);
            acc0        = __builtin_amdgcn_mfma_f32_32x32x16_bf16(w1f01, fr, acc0, 0, 0, 0);
            f32x16 acc1 = __builtin_amdgcn_mfma_f32_32x32x16_bf16(w1f10, fc, ZC, 0, 0, 0);
            acc1        = __builtin_amdgcn_mfma_f32_32x32x16_bf16(w1f11, fr, acc1, 0, 0, 0);

            // layer 2: p = pbase + sum_h n_h / D_h,  D_h = 1 + eb_h*exp2(acc_h)
            // quad common-denominator tree: 1 rcp per 4 h.
            float p = pbase;
#pragma unroll
            for (int q = 0; q < 8; ++q) {            // q 0..3 -> acc0, 4..7 -> acc1
                const f32x16& A = (q < 4) ? acc0 : acc1;
                int k = (q & 3) * 4;
                float4 c01 = t4[2 * q];              // eb0,n0,eb1,n1
                float4 c23 = t4[2 * q + 1];          // eb2,n2,eb3,n3
                float E0 = asm_exp2(A[k]);
                float E1 = asm_exp2(A[k + 1]);
                float E2 = asm_exp2(A[k + 2]);
                float E3 = asm_exp2(A[k + 3]);
                float D0 = fmaf(c01.x, E0, 1.0f);
                float D1 = fmaf(c01.z, E1, 1.0f);
                float D2 = fmaf(c23.x, E2, 1.0f);
                float D3 = fmaf(c23.z, E3, 1.0f);
                float D01 = D0 * D1;
                float D23 = D2 * D3;
                float N01 = fmaf(c01.y, D1, c01.w * D0);   // n0*D1 + n1*D0
                float N23 = fmaf(c23.y, D3, c23.w * D2);
                float N   = fmaf(N01, D23, N23 * D01);
                float P   = D01 * D23;
                p = fmaf(N, asm_rcp(P), p);
            }
            p += __shfl_xor(p, 32);
            float z = p + bias2;
            float res = asm_rcp(1.0f + asm_exp2(-z * LOG2E));

            unsigned eoff = ((unsigned)(t * 32 + l31)) << 2;
            if (EXACT) {
                if (lane < 32) *(float*)(outb + eoff) = res;
            } else {
                if (lane < 32 && (t * 32 + l31) < E) *(float*)(outb + eoff) = res;
            }

            if (tn >= ntiles) break;
            t = tn; tn = tnn;
            inx = inn; fc = fcn; fr = frn;
        }
    };

    if (idx64) body(BC<true>{});
    else       body(BC<false>{});
}

extern "C" void kernel_launch(void* const* d_in, const int* in_sizes, int n_in,
                              void* d_out, int out_size, void* d_ws, size_t ws_size,
                              hipStream_t stream)
{
    const float* x  = (const float*)d_in[0];
    const void*  ei = d_in[1];
    const float* W1 = (const float*)d_in[2];
    const float* b1 = (const float*)d_in[3];
    const float* W2 = (const float*)d_in[4];
    const float* b2 = (const float*)d_in[5];
    float* out = (float*)d_out;

    const int E      = in_sizes[1] / 2;
    const int nx     = in_sizes[0];
    const int ntiles = (E + 31) / 32;
    const bool exact = (E % 32) == 0;

    int* flag = nullptr;
    unsigned short* xb = nullptr;
    bool use_xb = false;
    if (ws_size >= 4) flag = (int*)d_ws;
    if (ws_size >= 256 + (size_t)nx * 2) {
        xb = (unsigned short*)((char*)d_ws + 256);
        use_xb = true;
    }

    if (use_xb) {
        int nth = (nx + 3) / 4;
        prep<<<(nth + 255) / 256, 256, 0, stream>>>(x, xb, nx, (const unsigned*)ei, flag);
    } else if (flag) {
        detect_idx64<<<1, 64, 0, stream>>>((const unsigned*)ei, flag);
    }

    // 1250 blocks = 5000 waves; 100000 tiles -> exactly 20 per wave (no ragged tail).
    int blocks = 1250;
    if (ntiles < blocks * 4) blocks = (ntiles + 3) / 4;   // small-E safety
    if (use_xb) {
        if (exact) edge_mlp<true , true ><<<blocks, 256, 0, stream>>>(ei, x, xb, W1, b1, W2, b2, out, flag, E, ntiles);
        else       edge_mlp<true , false><<<blocks, 256, 0, stream>>>(ei, x, xb, W1, b1, W2, b2, out, flag, E, ntiles);
    } else {
        if (exact) edge_mlp<false, true ><<<blocks, 256, 0, stream>>>(ei, x, xb, W1, b1, W2, b2, out, flag, E, ntiles);
        else       edge_mlp<false, false><<<blocks, 256, 0, stream>>>(ei, x, xb, W1, b1, W2, b2, out, flag, E, ntiles);
    }
}

// Round 8
// 60.289 us; speedup vs baseline: 1.2012x; 1.0391x over previous
//
#include <hip/hip_runtime.h>

// EdgeNetwork: out[e] = sigmoid( tanh( [x[col[e]], x[row[e]]] @ W1 + b1 ) @ W2 + b2 )
// E = 3.2M, IN=16, HID=64.
//
// R8 (base = R6, the last passing kernel; R7's __launch_bounds__(256,6) is
// REVERTED after a correctness failure):
//  1) Constant table hoisted to registers: the (eb,n) table is loop-invariant;
//     R5/R6 re-read it via 16x ds_read_b128 per tile inside the quad chain ->
//     ~120cy lgkm stalls consumed just-in-time. Now loaded ONCE pre-loop into
//     16 float4 regs; zero LDS traffic in the loop.
//  2) Pair-unroll: 2 tiles (64 edges) per iteration. Constants shared by both
//     epilogues; select-before-reduce gives ONE shfl_xor + ONE sigmoid + ONE
//     unpredicated fully-coalesced 64-lane store per pair.
// Carried: 32-edge mfma_32x32x16 swapped-operand tiles, quad common-denominator
// rcp tree, 32-bit addressing, 2-deep prefetch, asm exp2/rcp, EXACT path.
// Fallback single-tile kernel (R6 verbatim) when E % 64 != 0.

typedef __attribute__((ext_vector_type(8)))  short bf16x8;
typedef __attribute__((ext_vector_type(4)))  float f32x4;
typedef __attribute__((ext_vector_type(16))) float f32x16;
typedef __attribute__((ext_vector_type(4)))  unsigned short u16x4;

#define LOG2E 1.4426950408889634f

__device__ __forceinline__ float asm_exp2(float x) {
    float r;
    asm("v_exp_f32 %0, %1" : "=v"(r) : "v"(x));
    return r;
}
__device__ __forceinline__ float asm_rcp(float x) {
    float r;
    asm("v_rcp_f32 %0, %1" : "=v"(r) : "v"(x));
    return r;
}

template <bool B> struct BC { static constexpr bool value = B; };

__device__ __forceinline__ unsigned short f2bf(float f) {
    unsigned u = __float_as_uint(f);
    u += 0x7fffu + ((u >> 16) & 1u);
    return (unsigned short)(u >> 16);
}

// ---- x fp32 -> bf16, plus edge_index dtype detection (block 0, wave 0) ----
__global__ void prep(const float* __restrict__ x, unsigned short* __restrict__ xb, int n,
                     const unsigned* __restrict__ ei, int* __restrict__ flag) {
    if (blockIdx.x == 0 && threadIdx.x < 64) {
        unsigned v = ei[2 * threadIdx.x + 1];          // odd 32-bit words
        unsigned long long nz = __ballot(v != 0u);
        if (threadIdx.x == 0) flag[0] = (nz == 0ull) ? 1 : 0;
    }
    int i = (blockIdx.x * blockDim.x + threadIdx.x) * 4;
    if (i >= n) return;
    f32x4 v = *(const f32x4*)(x + i);
    u16x4 o;
    o[0] = f2bf(v[0]); o[1] = f2bf(v[1]); o[2] = f2bf(v[2]); o[3] = f2bf(v[3]);
    *(u16x4*)(xb + i) = o;
}

__global__ void detect_idx64(const unsigned* __restrict__ ei, int* __restrict__ flag) {
    unsigned v = ei[2 * threadIdx.x + 1];
    unsigned long long nz = __ballot(v != 0u);
    if (threadIdx.x == 0) flag[0] = (nz == 0ull) ? 1 : 0;
}

struct IdxPair { int c, r; };

// ===================== pair kernel (E % 64 == 0) =====================
template <bool USE_XB>
__global__ void __launch_bounds__(256)
edge_mlp_pair(const void* __restrict__ ei,
              const float* __restrict__ x,
              const unsigned short* __restrict__ xb,
              const float* __restrict__ W1,
              const float* __restrict__ b1,
              const float* __restrict__ W2,
              const float* __restrict__ b2,
              float* __restrict__ out,
              const int* __restrict__ flag,
              int E, int npairs)
{
    __shared__ float2 tbl[64];   // staging only; loop uses registers

    const int lane = threadIdx.x & 63;
    const int l31  = lane & 31;
    const int g    = lane >> 5;
    const int gwave  = blockIdx.x * (blockDim.x >> 6) + (threadIdx.x >> 6);
    const int nwaves = gridDim.x * (blockDim.x >> 6);

    const int idx64 = flag ? flag[0] : 0;
    const float S = 2.0f * LOG2E;

    {
        int tid = threadIdx.x;
        if (tid < 64) {
            int tg = tid >> 5, tb = (tid >> 4) & 1, tj = tid & 15;
            int rowv = (tj & 3) + 8 * (tj >> 2) + 4 * tg;
            int h = 32 * tb + rowv;
            float2 cw;
            cw.x = exp2f(S * b1[h]);
            cw.y = -2.0f * W2[h];
            tbl[tid] = cw;
        }
    }

    // A-fragments of S*W1T
    bf16x8 w1f00, w1f01, w1f10, w1f11;
    {
        union { bf16x8 v; unsigned short u[8]; } t00, t01, t10, t11;
#pragma unroll
        for (int b = 0; b < 8; ++b) {
            int k0 = 8 * g + b;
            t00.u[b] = f2bf(S * W1[(k0)      * 64 + l31]);
            t01.u[b] = f2bf(S * W1[(16 + k0) * 64 + l31]);
            t10.u[b] = f2bf(S * W1[(k0)      * 64 + 32 + l31]);
            t11.u[b] = f2bf(S * W1[(16 + k0) * 64 + 32 + l31]);
        }
        w1f00 = t00.v; w1f01 = t01.v; w1f10 = t10.v; w1f11 = t11.v;
    }

    float pbase = 0.f;
#pragma unroll
    for (int j = 0; j < 16; ++j) {
        int rowv = (j & 3) + 8 * (j >> 2) + 4 * g;
        pbase += W2[rowv] + W2[32 + rowv];
    }
    const float bias2 = b2[0];

    __syncthreads();

    // Hoist the whole per-lane constant table into registers (loop-invariant).
    float4 cc[16];
    {
        const float4* t4 = (const float4*)(&tbl[g * 32]);
#pragma unroll
        for (int j = 0; j < 16; ++j) cc[j] = t4[j];
    }

    const char* xbb  = (const char*)xb;
    const char* outb = (char*)out;
    const unsigned g16 = (unsigned)g << 4;

    auto body = [&](auto bc) {
        constexpr bool IDX64 = decltype(bc)::value;
        const unsigned sh = IDX64 ? 3u : 2u;
        const char* eiR = (const char*)ei;
        const char* eiC = (const char*)ei + ((size_t)E << sh);

        auto load_idx4 = [&](int pp, IdxPair& a, IdxPair& b) {
            unsigned base  = (((unsigned)pp << 6) + (unsigned)l31) << sh;
            unsigned baseB = base + (32u << sh);
            a.r = *(const int*)(eiR + base);
            a.c = *(const int*)(eiC + base);
            b.r = *(const int*)(eiR + baseB);
            b.c = *(const int*)(eiC + baseB);
        };
        auto gather = [&](int node) -> bf16x8 {
            if (USE_XB) {
                unsigned off = ((unsigned)node << 5) + g16;
                return *(const bf16x8*)(xbb + off);
            } else {
                const float* px = x + (size_t)node * 16 + 8 * g;
                f32x4 v0 = *(const f32x4*)px;
                f32x4 v1 = *(const f32x4*)(px + 4);
                union { bf16x8 v; unsigned short u[8]; } t;
#pragma unroll
                for (int b = 0; b < 4; ++b) { t.u[b] = f2bf(v0[b]); t.u[b + 4] = f2bf(v1[b]); }
                return t.v;
            }
        };

        auto quad = [&](const f32x16& A, int k, float4 c01, float4 c23, float& p) {
            float E0 = asm_exp2(A[k]);
            float E1 = asm_exp2(A[k + 1]);
            float E2 = asm_exp2(A[k + 2]);
            float E3 = asm_exp2(A[k + 3]);
            float D0 = fmaf(c01.x, E0, 1.0f);
            float D1 = fmaf(c01.z, E1, 1.0f);
            float D2 = fmaf(c23.x, E2, 1.0f);
            float D3 = fmaf(c23.z, E3, 1.0f);
            float D01 = D0 * D1;
            float D23 = D2 * D3;
            float N01 = fmaf(c01.y, D1, c01.w * D0);
            float N23 = fmaf(c23.y, D3, c23.w * D2);
            float N   = fmaf(N01, D23, N23 * D01);
            float P   = D01 * D23;
            p = fmaf(N, asm_rcp(P), p);
        };

        int pp = gwave;
        if (pp >= npairs) return;
        IdxPair iA, iB;
        load_idx4(pp, iA, iB);
        bf16x8 fcA = gather(iA.c), frA = gather(iA.r);
        bf16x8 fcB = gather(iB.c), frB = gather(iB.r);
        int pn = pp + nwaves;
        IdxPair iAn, iBn;
        load_idx4(pn < npairs ? pn : npairs - 1, iAn, iBn);

        const f32x16 ZC = 0.0f;

        while (true) {
            // prefetch: gathers for pair+1, indices for pair+2
            bf16x8 fcAn = gather(iAn.c), frAn = gather(iAn.r);
            bf16x8 fcBn = gather(iBn.c), frBn = gather(iBn.r);
            int pnn = pn + nwaves;
            IdxPair iAnn, iBnn;
            load_idx4(pnn < npairs ? pnn : npairs - 1, iAnn, iBnn);

            // ---- tile A ----
            float pA = pbase;
            {
                f32x16 a0 = __builtin_amdgcn_mfma_f32_32x32x16_bf16(w1f00, fcA, ZC, 0, 0, 0);
                a0        = __builtin_amdgcn_mfma_f32_32x32x16_bf16(w1f01, frA, a0, 0, 0, 0);
                f32x16 a1 = __builtin_amdgcn_mfma_f32_32x32x16_bf16(w1f10, fcA, ZC, 0, 0, 0);
                a1        = __builtin_amdgcn_mfma_f32_32x32x16_bf16(w1f11, frA, a1, 0, 0, 0);
#pragma unroll
                for (int q = 0; q < 4; ++q) quad(a0, q * 4, cc[2 * q],     cc[2 * q + 1], pA);
#pragma unroll
                for (int q = 0; q < 4; ++q) quad(a1, q * 4, cc[8 + 2 * q], cc[9 + 2 * q], pA);
            }
            // ---- tile B ----
            float pB = pbase;
            {
                f32x16 a0 = __builtin_amdgcn_mfma_f32_32x32x16_bf16(w1f00, fcB, ZC, 0, 0, 0);
                a0        = __builtin_amdgcn_mfma_f32_32x32x16_bf16(w1f01, frB, a0, 0, 0, 0);
                f32x16 a1 = __builtin_amdgcn_mfma_f32_32x32x16_bf16(w1f10, fcB, ZC, 0, 0, 0);
                a1        = __builtin_amdgcn_mfma_f32_32x32x16_bf16(w1f11, frB, a1, 0, 0, 0);
#pragma unroll
                for (int q = 0; q < 4; ++q) quad(a0, q * 4, cc[2 * q],     cc[2 * q + 1], pB);
#pragma unroll
                for (int q = 0; q < 4; ++q) quad(a1, q * 4, cc[8 + 2 * q], cc[9 + 2 * q], pB);
            }

            // select-before-reduce: lane's own tile partial + cross partial from lane^32
            float own   = g ? pB : pA;
            float cross = g ? pA : pB;
            own += __shfl_xor(cross, 32);
            float z = own + bias2;
            float res = asm_rcp(1.0f + asm_exp2(-z * LOG2E));

            // e = pp*64 + lane: one unpredicated, fully-coalesced 256B store
            unsigned eoff = (((unsigned)pp << 6) + (unsigned)lane) << 2;
            *(float*)(outb + eoff) = res;

            if (pn >= npairs) break;
            pp = pn; pn = pnn;
            iAn = iAnn; iBn = iBnn;
            fcA = fcAn; frA = frAn; fcB = fcBn; frB = frBn;
        }
    };

    if (idx64) body(BC<true>{});
    else       body(BC<false>{});
}

// ===================== fallback single-tile kernel (R6 verbatim) =====================
template <bool USE_XB, bool EXACT>
__global__ void __launch_bounds__(256)
edge_mlp1(const void* __restrict__ ei,
          const float* __restrict__ x,
          const unsigned short* __restrict__ xb,
          const float* __restrict__ W1,
          const float* __restrict__ b1,
          const float* __restrict__ W2,
          const float* __restrict__ b2,
          float* __restrict__ out,
          const int* __restrict__ flag,
          int E, int ntiles)
{
    __shared__ float2 tbl[64];

    const int lane = threadIdx.x & 63;
    const int l31  = lane & 31;
    const int g    = lane >> 5;
    const int gwave  = blockIdx.x * (blockDim.x >> 6) + (threadIdx.x >> 6);
    const int nwaves = gridDim.x * (blockDim.x >> 6);

    const int idx64 = flag ? flag[0] : 0;
    const float S = 2.0f * LOG2E;

    {
        int tid = threadIdx.x;
        if (tid < 64) {
            int tg = tid >> 5, tb = (tid >> 4) & 1, tj = tid & 15;
            int rowv = (tj & 3) + 8 * (tj >> 2) + 4 * tg;
            int h = 32 * tb + rowv;
            float2 cw;
            cw.x = exp2f(S * b1[h]);
            cw.y = -2.0f * W2[h];
            tbl[tid] = cw;
        }
    }

    bf16x8 w1f00, w1f01, w1f10, w1f11;
    {
        union { bf16x8 v; unsigned short u[8]; } t00, t01, t10, t11;
#pragma unroll
        for (int b = 0; b < 8; ++b) {
            int k0 = 8 * g + b;
            t00.u[b] = f2bf(S * W1[(k0)      * 64 + l31]);
            t01.u[b] = f2bf(S * W1[(16 + k0) * 64 + l31]);
            t10.u[b] = f2bf(S * W1[(k0)      * 64 + 32 + l31]);
            t11.u[b] = f2bf(S * W1[(16 + k0) * 64 + 32 + l31]);
        }
        w1f00 = t00.v; w1f01 = t01.v; w1f10 = t10.v; w1f11 = t11.v;
    }

    float pbase = 0.f;
#pragma unroll
    for (int j = 0; j < 16; ++j) {
        int rowv = (j & 3) + 8 * (j >> 2) + 4 * g;
        pbase += W2[rowv] + W2[32 + rowv];
    }
    const float bias2 = b2[0];

    __syncthreads();
    const float4* t4 = (const float4*)(&tbl[g * 32]);

    const char* xbb  = (const char*)xb;
    const char* outb = (char*)out;
    const unsigned g16 = (unsigned)g << 4;

    auto body = [&](auto bc) {
        constexpr bool IDX64 = decltype(bc)::value;
        const unsigned sh = IDX64 ? 3u : 2u;
        const char* eiR = (const char*)ei;
        const char* eiC = (const char*)ei + ((size_t)E << sh);

        auto load_idx = [&](int tt) -> IdxPair {
            int e = tt * 32 + l31;
            unsigned ec;
            if (EXACT) ec = (unsigned)e;
            else       ec = (unsigned)(e < E ? e : E - 1);
            unsigned off = ec << sh;
            IdxPair ip;
            ip.r = *(const int*)(eiR + off);
            ip.c = *(const int*)(eiC + off);
            return ip;
        };
        auto gather = [&](int node) -> bf16x8 {
            if (USE_XB) {
                unsigned off = ((unsigned)node << 5) + g16;
                return *(const bf16x8*)(xbb + off);
            } else {
                const float* px = x + (size_t)node * 16 + 8 * g;
                f32x4 v0 = *(const f32x4*)px;
                f32x4 v1 = *(const f32x4*)(px + 4);
                union { bf16x8 v; unsigned short u[8]; } t;
#pragma unroll
                for (int b = 0; b < 4; ++b) { t.u[b] = f2bf(v0[b]); t.u[b + 4] = f2bf(v1[b]); }
                return t.v;
            }
        };

        auto quad = [&](const f32x16& A, int k, float4 c01, float4 c23, float& p) {
            float E0 = asm_exp2(A[k]);
            float E1 = asm_exp2(A[k + 1]);
            float E2 = asm_exp2(A[k + 2]);
            float E3 = asm_exp2(A[k + 3]);
            float D0 = fmaf(c01.x, E0, 1.0f);
            float D1 = fmaf(c01.z, E1, 1.0f);
            float D2 = fmaf(c23.x, E2, 1.0f);
            float D3 = fmaf(c23.z, E3, 1.0f);
            float D01 = D0 * D1;
            float D23 = D2 * D3;
            float N01 = fmaf(c01.y, D1, c01.w * D0);
            float N23 = fmaf(c23.y, D3, c23.w * D2);
            float N   = fmaf(N01, D23, N23 * D01);
            float P   = D01 * D23;
            p = fmaf(N, asm_rcp(P), p);
        };

        int t = gwave;
        if (t >= ntiles) return;
        IdxPair ic = load_idx(t);
        bf16x8 fc = gather(ic.c);
        bf16x8 fr = gather(ic.r);
        int tn = t + nwaves;
        IdxPair inx = load_idx(tn < ntiles ? tn : ntiles - 1);

        const f32x16 ZC = 0.0f;

        while (true) {
            bf16x8 fcn = gather(inx.c);
            bf16x8 frn = gather(inx.r);
            int tnn = tn + nwaves;
            IdxPair inn = load_idx(tnn < ntiles ? tnn : ntiles - 1);

            f32x16 acc0 = __builtin_amdgcn_mfma_f32_32x32x16_bf16(w1f00, fc, ZC, 0, 0, 0);
            acc0        = __builtin_amdgcn_mfma_f32_32x32x16_bf16(w1f01, fr, acc0, 0, 0, 0);
            f32x16 acc1 = __builtin_amdgcn_mfma_f32_32x32x16_bf16(w1f10, fc, ZC, 0, 0, 0);
            acc1        = __builtin_amdgcn_mfma_f32_32x32x16_bf16(w1f11, fr, acc1, 0, 0, 0);

            float p = pbase;
#pragma unroll
            for (int q = 0; q < 4; ++q) quad(acc0, q * 4, t4[2 * q],     t4[2 * q + 1], p);
#pragma unroll
            for (int q = 0; q < 4; ++q) quad(acc1, q * 4, t4[8 + 2 * q], t4[9 + 2 * q], p);

            p += __shfl_xor(p, 32);
            float z = p + bias2;
            float res = asm_rcp(1.0f + asm_exp2(-z * LOG2E));

            unsigned eoff = ((unsigned)(t * 32 + l31)) << 2;
            if (EXACT) {
                if (lane < 32) *(float*)(outb + eoff) = res;
            } else {
                if (lane < 32 && (t * 32 + l31) < E) *(float*)(outb + eoff) = res;
            }

            if (tn >= ntiles) break;
            t = tn; tn = tnn;
            inx = inn; fc = fcn; fr = frn;
        }
    };

    if (idx64) body(BC<true>{});
    else       body(BC<false>{});
}

extern "C" void kernel_launch(void* const* d_in, const int* in_sizes, int n_in,
                              void* d_out, int out_size, void* d_ws, size_t ws_size,
                              hipStream_t stream)
{
    const float* x  = (const float*)d_in[0];
    const void*  ei = d_in[1];
    const float* W1 = (const float*)d_in[2];
    const float* b1 = (const float*)d_in[3];
    const float* W2 = (const float*)d_in[4];
    const float* b2 = (const float*)d_in[5];
    float* out = (float*)d_out;

    const int E      = in_sizes[1] / 2;
    const int nx     = in_sizes[0];
    const int ntiles = (E + 31) / 32;

    int* flag = nullptr;
    unsigned short* xb = nullptr;
    bool use_xb = false;
    if (ws_size >= 4) flag = (int*)d_ws;
    if (ws_size >= 256 + (size_t)nx * 2) {
        xb = (unsigned short*)((char*)d_ws + 256);
        use_xb = true;
    }

    if (use_xb) {
        int nth = (nx + 3) / 4;
        prep<<<(nth + 255) / 256, 256, 0, stream>>>(x, xb, nx, (const unsigned*)ei, flag);
    } else if (flag) {
        detect_idx64<<<1, 64, 0, stream>>>((const unsigned*)ei, flag);
    }

    if ((E & 63) == 0) {
        // pair kernel: 64 edges per wave-iteration
        const int npairs = E / 64;
        int blocks = 768;                      // 3072 waves; ~3 waves/SIMD resident
        if (npairs < blocks * 4) blocks = (npairs + 3) / 4;
        if (blocks < 1) blocks = 1;
        if (use_xb)
            edge_mlp_pair<true ><<<blocks, 256, 0, stream>>>(ei, x, xb, W1, b1, W2, b2, out, flag, E, npairs);
        else
            edge_mlp_pair<false><<<blocks, 256, 0, stream>>>(ei, x, xb, W1, b1, W2, b2, out, flag, E, npairs);
    } else {
        const bool exact = (E % 32) == 0;
        int blocks = 1250;
        if (ntiles < blocks * 4) blocks = (ntiles + 3) / 4;
        if (blocks < 1) blocks = 1;
        if (use_xb) {
            if (exact) edge_mlp1<true , true ><<<blocks, 256, 0, stream>>>(ei, x, xb, W1, b1, W2, b2, out, flag, E, ntiles);
            else       edge_mlp1<true , false><<<blocks, 256, 0, stream>>>(ei, x, xb, W1, b1, W2, b2, out, flag, E, ntiles);
        } else {
            if (exact) edge_mlp1<false, true ><<<blocks, 256, 0, stream>>>(ei, x, xb, W1, b1, W2, b2, out, flag, E, ntiles);
            else       edge_mlp1<false, false><<<blocks, 256, 0, stream>>>(ei, x, xb, W1, b1, W2, b2, out, flag, E, ntiles);
        }
    }
}